// Round 8
// baseline (367.914 us; speedup 1.0000x reference)
//
#include <hip/hip_runtime.h>
#include <hip/hip_bf16.h>
#include <stdint.h>

#define S_LEN 1024
#define E_DIM 768
#define H_N   12
#define FF_DIM 3072

typedef __hip_bfloat16 bf16;
using short8  = __attribute__((ext_vector_type(8))) short;
using short4v = __attribute__((ext_vector_type(4))) short;
using f32x4   = __attribute__((ext_vector_type(4))) float;

__device__ __forceinline__ void async_cp16(const void* g, void* l) {
  __builtin_amdgcn_global_load_lds(
      (__attribute__((address_space(1))) void*)(g),
      (__attribute__((address_space(3))) void*)(l), 16, 0, 0);
}

// ---------------- weight transpose + cast: wt[n][k] = bf16(w[k][n]) ----------
__global__ __launch_bounds__(256) void wcastT(const float* __restrict__ w,
                                              bf16* __restrict__ wt,
                                              int K, int N) {
  __shared__ float t[32][33];
  int bx = blockIdx.x;          // n tile
  int by = blockIdx.y;          // k tile
  int x = threadIdx.x & 31;
  int y = threadIdx.x >> 5;     // 0..7
  for (int i = y; i < 32; i += 8)
    t[i][x] = w[(size_t)(by * 32 + i) * N + bx * 32 + x];
  __syncthreads();
  for (int i = y; i < 32; i += 8)
    wt[(size_t)(bx * 32 + i) * K + by * 32 + x] = __float2bfloat16(t[x][i]);
}

// ---------------- layernorm over E=768, out bf16 -----------------------------
__global__ __launch_bounds__(256) void ln_rows(const float* __restrict__ x,
                                               const float* __restrict__ g,
                                               const float* __restrict__ b,
                                               bf16* __restrict__ out) {
  int row = blockIdx.x;
  int tid = threadIdx.x;
  const float* xr = x + (size_t)row * E_DIM;
  float v0 = xr[tid], v1 = xr[tid + 256], v2 = xr[tid + 512];
  float s = v0 + v1 + v2;
  float ss = v0 * v0 + v1 * v1 + v2 * v2;
  for (int o = 32; o > 0; o >>= 1) {
    s  += __shfl_down(s, o);
    ss += __shfl_down(ss, o);
  }
  __shared__ float ps[4], pq[4];
  int wv = tid >> 6;
  if ((tid & 63) == 0) { ps[wv] = s; pq[wv] = ss; }
  __syncthreads();
  s  = ps[0] + ps[1] + ps[2] + ps[3];
  ss = pq[0] + pq[1] + pq[2] + pq[3];
  float mu  = s * (1.0f / E_DIM);
  float var = ss * (1.0f / E_DIM) - mu * mu;
  float rs  = rsqrtf(var + 1e-5f);
  bf16* orow = out + (size_t)row * E_DIM;
  orow[tid]       = __float2bfloat16((v0 - mu) * rs * g[tid]       + b[tid]);
  orow[tid + 256] = __float2bfloat16((v1 - mu) * rs * g[tid + 256] + b[tid + 256]);
  orow[tid + 512] = __float2bfloat16((v2 - mu) * rs * g[tid + 512] + b[tid + 512]);
}

// ---------------- GEMM 128x128: C[M,N] = A[M,K] @ Bt[N,K]^T ------------------
// Pipelined K-loop: ONE barrier/step, double-buffered LDS, prefetch issued
// after the fragment ds_reads (prefetch latency hidden behind compute).
// BK=64, XOR-swizzled LDS columns, XCD-aware 1-D grid.
// MFMA operands swapped: lane's 4 acc regs = 4 consecutive N-cols of one row.
// MODE 0: qkv scatter; MODE 2: gelu -> bf16.
template <int MODE>
__global__ __launch_bounds__(256) void gemm_bt(
    const bf16* __restrict__ A, const bf16* __restrict__ Bt,
    const float* __restrict__ bias, const float* __restrict__ resid,
    float* __restrict__ outf, bf16* __restrict__ ob0, bf16* __restrict__ ob1,
    bf16* __restrict__ ob2, int M, int N, int K) {
  __shared__ bf16 As[2][128 * 64];   // 32 KB
  __shared__ bf16 Bs[2][128 * 64];   // 32 KB
  int tid = threadIdx.x;
  int wave = tid >> 6, lane = tid & 63;
  int quad = lane >> 4, l16 = lane & 15;
  int gx = N >> 7;
  int flat = blockIdx.x;
  int y8 = flat & 7;
  int q2 = flat >> 3;
  int bx = q2 % gx;
  int by = (q2 / gx) * 8 + y8;
  int m0 = by * 128, n0 = bx * 128;
  int wm = (wave & 1) * 64, wn = (wave >> 1) * 64;
  f32x4 acc[4][4];
  for (int i = 0; i < 4; i++)
    for (int j = 0; j < 4; j++)
      for (int r = 0; r < 4; r++) acc[i][j][r] = 0.f;

  int xs = l16 & 7;                 // fragment-read XOR key
  // staging geometry: c = t*256+tid -> row = t*32 + (tid>>3), chunk = tid&7
  // row&7 == (tid>>3)&7 for all t, so swizzled col is t-invariant
  int srow = tid >> 3;
  int cg = (((tid & 7) ^ (srow & 7)) << 3);
  const bf16* aptr = A  + (size_t)(m0 + srow) * K + cg;
  const bf16* bptr = Bt + (size_t)(n0 + srow) * K + cg;

  int nkb = K >> 6;
  // prologue: stage k-block 0 into buf 0
  {
    bf16* la = &As[0][0] + tid * 8;
    bf16* lb = &Bs[0][0] + tid * 8;
#pragma unroll
    for (int t = 0; t < 4; ++t) {
      async_cp16(aptr + (size_t)t * 32 * K, la + t * 2048);
      async_cp16(bptr + (size_t)t * 32 * K, lb + t * 2048);
    }
  }
  for (int ik = 0; ik < nkb; ++ik) {
    int cur = ik & 1;
    __syncthreads();   // drains loads issued a full iteration ago (cheap)
    // read ALL fragments of current buffer first (no alias hazard w/ prefetch)
    short8 af[2][4], bfr[2][4];
#pragma unroll
    for (int ks = 0; ks < 2; ks++) {
      int ko = (((ks * 4 + quad) ^ xs) << 3);
      for (int i = 0; i < 4; i++)
        af[ks][i] = *(const short8*)&As[cur][(wm + i * 16 + l16) * 64 + ko];
      for (int j = 0; j < 4; j++)
        bfr[ks][j] = *(const short8*)&Bs[cur][(wn + j * 16 + l16) * 64 + ko];
    }
    // prefetch next k-block into the other buffer
    if (ik + 1 < nkb) {
      size_t ko = (size_t)(ik + 1) * 64;
      bf16* la = &As[cur ^ 1][0] + tid * 8;
      bf16* lb = &Bs[cur ^ 1][0] + tid * 8;
#pragma unroll
      for (int t = 0; t < 4; ++t) {
        async_cp16(aptr + ko + (size_t)t * 32 * K, la + t * 2048);
        async_cp16(bptr + ko + (size_t)t * 32 * K, lb + t * 2048);
      }
    }
#pragma unroll
    for (int ks = 0; ks < 2; ks++)
      for (int i = 0; i < 4; i++)
        for (int j = 0; j < 4; j++)
          acc[i][j] = __builtin_amdgcn_mfma_f32_16x16x32_bf16(
              bfr[ks][j], af[ks][i], acc[i][j], 0, 0, 0);
  }

  for (int j = 0; j < 4; j++) {
    int colb = n0 + wn + j * 16 + quad * 4;          // 4 consecutive cols
    f32x4 b4 = *(const f32x4*)&bias[colb];
    for (int i = 0; i < 4; i++) {
      int row = m0 + wm + i * 16 + l16;
      f32x4 v = acc[i][j] + b4;
      if (MODE == 0) {
        int nn = row >> 10, s = row & 1023;
        if (colb < 768) {
          int h = colb >> 6, db = colb & 63;
          short4v pk;
          for (int r = 0; r < 4; r++)
            pk[r] = __builtin_bit_cast(short, __float2bfloat16(v[r] * 0.125f));
          *(short4v*)&ob0[(((size_t)nn * H_N + h) * S_LEN + s) * 64 + db] = pk;
        } else if (colb < 1536) {
          int c = colb - 768;
          size_t nh2 = (size_t)nn * H_N + (c >> 6);
          int d = c & 63;
          short4v pk;
          for (int r = 0; r < 4; r++)
            pk[r] = __builtin_bit_cast(short, __float2bfloat16(v[r]));
          *(short4v*)&ob1[((nh2 * 8 + (d >> 3)) * S_LEN + s) * 8 + (d & 7)] = pk;
        } else {
          int c = colb - 1536;
          size_t nh2 = (size_t)nn * H_N + (c >> 6);
          int d0 = c & 63;
          for (int r = 0; r < 4; r++)
            ob2[((nh2 * 128 + (s >> 3)) * 64 + d0 + r) * 8 + (s & 7)] =
                __float2bfloat16(v[r]);
        }
      } else if (MODE == 2) {
        short4v pk;
        for (int r = 0; r < 4; r++) {
          float x = v[r];
          // tanh-form GELU: x * sigmoid(1.5957691*(x + 0.044715 x^3))
          float t = x * (1.59576912161f + 0.0713548162726f * x * x);
          float g = x * __builtin_amdgcn_rcpf(1.0f + __expf(-t));
          pk[r] = __builtin_bit_cast(short, __float2bfloat16(g));
        }
        *(short4v*)&ob0[(size_t)row * N + colb] = pk;
      }
    }
  }
}

// ---------------- GEMM 128x64 pipelined: outf = A@Bt^T + bias + resid --------
// For N=768 GEMMs (proj, FC2): 768 blocks = 3/CU. LDS 48 KB dbuf.
__global__ __launch_bounds__(256) void gemm_bt64(
    const bf16* __restrict__ A, const bf16* __restrict__ Bt,
    const float* __restrict__ bias, const float* __restrict__ resid,
    float* __restrict__ outf, int M, int N, int K) {
  __shared__ bf16 As[2][128 * 64];   // 32 KB
  __shared__ bf16 Bs[2][64 * 64];    // 16 KB
  int tid = threadIdx.x;
  int wave = tid >> 6, lane = tid & 63;
  int quad = lane >> 4, l16 = lane & 15;
  int gx = N >> 6;                  // 12
  int flat = blockIdx.x;
  int y8 = flat & 7;
  int q2 = flat >> 3;
  int bx = q2 % gx;
  int by = (q2 / gx) * 8 + y8;
  int m0 = by * 128, n0 = bx * 64;
  int wm = wave * 32;               // wave owns 32 M-rows, all 64 N-cols
  f32x4 acc[2][4];
  for (int i = 0; i < 2; i++)
    for (int j = 0; j < 4; j++)
      for (int r = 0; r < 4; r++) acc[i][j][r] = 0.f;

  int xs = l16 & 7;
  int srow = tid >> 3;
  int cg = (((tid & 7) ^ (srow & 7)) << 3);
  const bf16* aptr = A  + (size_t)(m0 + srow) * K + cg;
  const bf16* bptr = Bt + (size_t)(n0 + srow) * K + cg;

  int nkb = K >> 6;
  {
    bf16* la = &As[0][0] + tid * 8;
    bf16* lb = &Bs[0][0] + tid * 8;
#pragma unroll
    for (int t = 0; t < 4; ++t)
      async_cp16(aptr + (size_t)t * 32 * K, la + t * 2048);
#pragma unroll
    for (int t = 0; t < 2; ++t)
      async_cp16(bptr + (size_t)t * 32 * K, lb + t * 2048);
  }
  for (int ik = 0; ik < nkb; ++ik) {
    int cur = ik & 1;
    __syncthreads();
    short8 af[2][2], bfr[2][4];
#pragma unroll
    for (int ks = 0; ks < 2; ks++) {
      int ko = (((ks * 4 + quad) ^ xs) << 3);
      for (int i = 0; i < 2; i++)
        af[ks][i] = *(const short8*)&As[cur][(wm + i * 16 + l16) * 64 + ko];
      for (int j = 0; j < 4; j++)
        bfr[ks][j] = *(const short8*)&Bs[cur][(j * 16 + l16) * 64 + ko];
    }
    if (ik + 1 < nkb) {
      size_t ko = (size_t)(ik + 1) * 64;
      bf16* la = &As[cur ^ 1][0] + tid * 8;
      bf16* lb = &Bs[cur ^ 1][0] + tid * 8;
#pragma unroll
      for (int t = 0; t < 4; ++t)
        async_cp16(aptr + ko + (size_t)t * 32 * K, la + t * 2048);
#pragma unroll
      for (int t = 0; t < 2; ++t)
        async_cp16(bptr + ko + (size_t)t * 32 * K, lb + t * 2048);
    }
#pragma unroll
    for (int ks = 0; ks < 2; ks++)
      for (int i = 0; i < 2; i++)
        for (int j = 0; j < 4; j++)
          acc[i][j] = __builtin_amdgcn_mfma_f32_16x16x32_bf16(
              bfr[ks][j], af[ks][i], acc[i][j], 0, 0, 0);
  }

  for (int j = 0; j < 4; j++) {
    int colb = n0 + j * 16 + quad * 4;
    f32x4 b4 = *(const f32x4*)&bias[colb];
    for (int i = 0; i < 2; i++) {
      int row = m0 + wm + i * 16 + l16;
      size_t idx = (size_t)row * N + colb;
      f32x4 rv = *(const f32x4*)&resid[idx];
      *(f32x4*)&outf[idx] = acc[i][j] + b4 + rv;
    }
  }
}

// ---------------- flash attention v4: paired q-tiles, pipelined K/V ----------
// Paired q-tiles a & 15-a (uniform 17 k-tiles/block). No-max softmax
// (acc init -10, exact shift). Head-per-XCD swizzle. K/V staging double-
// buffered: one barrier per k-tile, prefetch after fragment reads.
__global__ __launch_bounds__(256) void attn_fwd(
    const bf16* __restrict__ q, const bf16* __restrict__ kg,
    const bf16* __restrict__ vg, bf16* __restrict__ out) {
  __shared__ bf16 kt2[2][8 * 64 * 8];  // 16 KB
  __shared__ bf16 vt2[2][8 * 64 * 8];  // 16 KB
  __shared__ bf16 pba[4][16 * 68];     // per-wave P, tile a (8.5 KB)
  __shared__ bf16 pbb[4][16 * 68];     // per-wave P, tile b (8.5 KB)
  int flat = blockIdx.x;             // 768 blocks
  int xcd = flat & 7;
  int j = flat >> 3;                 // 0..95
  int a = j & 7;                     // low q-tile 0..7
  int g = j >> 3;                    // 0..11
  int nh = xcd * 12 + g;             // head: all its blocks share flat&7
  int b = 15 - a;                    // high q-tile 8..15
  int n = nh / H_N, h = nh % H_N;
  int tid = threadIdx.x, wave = tid >> 6, lane = tid & 63;
  int quad = lane >> 4, l16 = lane & 15;
  const bf16* qp = q  + (size_t)nh * S_LEN * 64;
  const bf16* kp = kg + (size_t)nh * 8 * S_LEN * 8;
  const bf16* vp = vg + (size_t)nh * 128 * 64 * 8;
  int qra = a * 64 + wave * 16;      // tile-a wave rows; lane's q = qra + l16
  int qrb = b * 64 + wave * 16;

  short8 qfa[2], qfb[2];
  qfa[0] = *(const short8*)&qp[(size_t)(qra + l16) * 64 + quad * 8];
  qfa[1] = *(const short8*)&qp[(size_t)(qra + l16) * 64 + 32 + quad * 8];
  qfb[0] = *(const short8*)&qp[(size_t)(qrb + l16) * 64 + quad * 8];
  qfb[1] = *(const short8*)&qp[(size_t)(qrb + l16) * 64 + 32 + quad * 8];

  // staging pointers: slot s = t*256+tid, c = s>>6 = t*4 + (tid>>6), e = tid&63
  const bf16* kbase = kp + (((size_t)(tid >> 6) * S_LEN) + (tid & 63)) * 8;
  const bf16* vbase = vp + (((size_t)(tid >> 6) * 64) + (tid & 63)) * 8;

  f32x4 oaa[4], oab[4];              // O^T: d = dt*16+quad*4+r, q = l16
  for (int dt = 0; dt < 4; dt++)
    for (int r = 0; r < 4; r++) { oaa[dt][r] = 0.f; oab[dt][r] = 0.f; }
  float lia = 0.f, lib = 0.f;

  // prologue: stage k-tile 0 into buf 0
  {
    bf16* lk = &kt2[0][0] + tid * 8;
    bf16* lv = &vt2[0][0] + tid * 8;
#pragma unroll
    for (int t = 0; t < 2; ++t) {
      async_cp16(kbase + (size_t)t * 4 * S_LEN * 8, lk + t * 2048);
      async_cp16(vbase + (size_t)t * 2048, lv + t * 2048);
    }
  }

  for (int kb = 0; kb <= b; ++kb) {
    bool act_a = (kb <= a);
    int cur = kb & 1;
    __syncthreads();   // drains prefetch issued last iteration (cheap)

    // read ALL K/V fragments of current buffer into registers first
    short8 kf[2][4], vf[2][4];
#pragma unroll
    for (int ks = 0; ks < 2; ks++)
      for (int nt = 0; nt < 4; nt++) {
        kf[ks][nt] = *(const short8*)
            &kt2[cur][(size_t)((ks * 4 + quad) * 64 + nt * 16 + l16) * 8];
        vf[ks][nt] = *(const short8*)
            &vt2[cur][(size_t)((ks * 4 + quad) * 64 + nt * 16 + l16) * 8];
      }
    // prefetch next k-tile into the other buffer
    if (kb < b) {
      bf16* lk = &kt2[cur ^ 1][0] + tid * 8;
      bf16* lv = &vt2[cur ^ 1][0] + tid * 8;
      size_t kko = (size_t)(kb + 1) * 512;    // kb*64*8 elements
      size_t vko = (size_t)(kb + 1) * 4096;   // kb*8*64*8 elements
#pragma unroll
      for (int t = 0; t < 2; ++t) {
        async_cp16(kbase + kko + (size_t)t * 4 * S_LEN * 8, lk + t * 2048);
        async_cp16(vbase + vko + (size_t)t * 2048, lv + t * 2048);
      }
    }

    // S^T = K·Q^T for both tiles; acc starts at -10 (softmax shift)
    f32x4 sb4[4], sa4[4];
    for (int nt = 0; nt < 4; nt++) {
      for (int r = 0; r < 4; r++) { sb4[nt][r] = -10.f; sa4[nt][r] = -10.f; }
      for (int ks = 0; ks < 2; ks++) {
        sb4[nt] = __builtin_amdgcn_mfma_f32_16x16x32_bf16(kf[ks][nt], qfb[ks],
                                                          sb4[nt], 0, 0, 0);
        if (act_a)
          sa4[nt] = __builtin_amdgcn_mfma_f32_16x16x32_bf16(kf[ks][nt], qfa[ks],
                                                            sa4[nt], 0, 0, 0);
      }
    }
    if (kb == b) {   // diagonal of tile b
      int ql = wave * 16 + l16;
      for (int nt = 0; nt < 4; nt++)
        for (int r = 0; r < 4; r++)
          if (nt * 16 + quad * 4 + r > ql) sb4[nt][r] = -INFINITY;
    }
    if (kb == a) {   // diagonal of tile a
      int ql = wave * 16 + l16;
      for (int nt = 0; nt < 4; nt++)
        for (int r = 0; r < 4; r++)
          if (nt * 16 + quad * 4 + r > ql) sa4[nt][r] = -INFINITY;
    }

    // no-max softmax: p = e^{s-10}; row sum via 2 shuffles
    float rsb = 0.f;
    for (int nt = 0; nt < 4; nt++)
      for (int r = 0; r < 4; r++) {
        float p = __expf(sb4[nt][r]);
        sb4[nt][r] = p;
        rsb += p;
      }
    rsb += __shfl_xor(rsb, 16);
    rsb += __shfl_xor(rsb, 32);
    lib += rsb;
    bf16* pwb = pbb[wave];
    for (int nt = 0; nt < 4; nt++) {
      short4v pk;
      for (int r = 0; r < 4; r++)
        pk[r] = __builtin_bit_cast(short, __float2bfloat16(sb4[nt][r]));
      *(short4v*)&pwb[l16 * 68 + nt * 16 + quad * 4] = pk;
    }
    if (act_a) {
      float rsa = 0.f;
      for (int nt = 0; nt < 4; nt++)
        for (int r = 0; r < 4; r++) {
          float p = __expf(sa4[nt][r]);
          sa4[nt][r] = p;
          rsa += p;
        }
      rsa += __shfl_xor(rsa, 16);
      rsa += __shfl_xor(rsa, 32);
      lia += rsa;
      bf16* pwa = pba[wave];
      for (int nt = 0; nt < 4; nt++) {
        short4v pk;
        for (int r = 0; r < 4; r++)
          pk[r] = __builtin_bit_cast(short, __float2bfloat16(sa4[nt][r]));
        *(short4v*)&pwa[l16 * 68 + nt * 16 + quad * 4] = pk;
      }
    }
    asm volatile("s_waitcnt lgkmcnt(0)" ::: "memory");  // same-wave LDS RAW

    // O^T += V^T·P^T
    for (int ks = 0; ks < 2; ks++) {
      short8 pfb = *(const short8*)&pbb[wave][l16 * 68 + ks * 32 + quad * 8];
      short8 pfa;
      if (act_a) pfa = *(const short8*)&pba[wave][l16 * 68 + ks * 32 + quad * 8];
      for (int dt = 0; dt < 4; dt++) {
        oab[dt] = __builtin_amdgcn_mfma_f32_16x16x32_bf16(vf[ks][dt], pfb,
                                                          oab[dt], 0, 0, 0);
        if (act_a)
          oaa[dt] = __builtin_amdgcn_mfma_f32_16x16x32_bf16(vf[ks][dt], pfa,
                                                            oaa[dt], 0, 0, 0);
      }
    }
  }

  float inva = 1.0f / lia, invb = 1.0f / lib;
  int ta = n * S_LEN + qra + l16;
  int tb = n * S_LEN + qrb + l16;
  for (int dt = 0; dt < 4; dt++) {
    short4v ova, ovb;
    for (int r = 0; r < 4; r++) {
      ova[r] = __builtin_bit_cast(short, __float2bfloat16(oaa[dt][r] * inva));
      ovb[r] = __builtin_bit_cast(short, __float2bfloat16(oab[dt][r] * invb));
    }
    *(short4v*)&out[(size_t)ta * E_DIM + h * 64 + dt * 16 + quad * 4] = ova;
    *(short4v*)&out[(size_t)tb * E_DIM + h * 64 + dt * 16 + quad * 4] = ovb;
  }
}

extern "C" void kernel_launch(void* const* d_in, const int* in_sizes, int n_in,
                              void* d_out, int out_size, void* d_ws, size_t ws_size,
                              hipStream_t stream) {
  (void)in_sizes; (void)n_in; (void)out_size; (void)ws_size;
  const float* x      = (const float*)d_in[0];
  const float* ln1_g  = (const float*)d_in[1];
  const float* ln1_b  = (const float*)d_in[2];
  const float* ln2_g  = (const float*)d_in[3];
  const float* ln2_b  = (const float*)d_in[4];
  const float* w_attn = (const float*)d_in[5];
  const float* b_attn = (const float*)d_in[6];
  const float* w_proj = (const float*)d_in[7];
  const float* b_proj = (const float*)d_in[8];
  const float* w_fc   = (const float*)d_in[9];
  const float* b_fc   = (const float*)d_in[10];
  const float* w_fc2  = (const float*)d_in[11];
  const float* b_fc2  = (const float*)d_in[12];
  float* out = (float*)d_out;

  char* ws = (char*)d_ws;
  bf16* wt_attn = (bf16*)(ws);                 //  3,538,944 B
  bf16* wt_proj = (bf16*)(ws + 3538944);       //  1,179,648 B
  bf16* wt_fc   = (bf16*)(ws + 4718592);       //  4,718,592 B
  bf16* wt_fc2  = (bf16*)(ws + 9437184);       //  4,718,592 B
  bf16* hbuf    = (bf16*)(ws + 14155776);      // 12,582,912 B
  float* x2     = (float*)(ws + 26738688);     // 25,165,824 B
  bf16* qb      = (bf16*)(ws + 51904512);      // 12,582,912 B
  bf16* kbuf    = (bf16*)(ws + 64487424);      // 12,582,912 B (chunked kg)
  bf16* vtb     = (bf16*)(ws + 77070336);      // 12,582,912 B (chunked vg)
  bf16* ao      = (bf16*)(ws + 89653248);      // 12,582,912 B  (ends 102,236,160)
  bf16* ff      = qb;  // reuse q/k/v/ao region (50,331,648 B needed)

  dim3 blk(256);
  wcastT<<<dim3(2304 / 32, 768 / 32), blk, 0, stream>>>(w_attn, wt_attn, 768, 2304);
  wcastT<<<dim3(768 / 32, 768 / 32), blk, 0, stream>>>(w_proj, wt_proj, 768, 768);
  wcastT<<<dim3(3072 / 32, 768 / 32), blk, 0, stream>>>(w_fc, wt_fc, 768, 3072);
  wcastT<<<dim3(768 / 32, 3072 / 32), blk, 0, stream>>>(w_fc2, wt_fc2, 3072, 768);

  ln_rows<<<8192, blk, 0, stream>>>(x, ln1_g, ln1_b, hbuf);

  gemm_bt<0><<<dim3(18 * 64), blk, 0, stream>>>(
      hbuf, wt_attn, b_attn, nullptr, nullptr, qb, kbuf, vtb, 8192, 2304, 768);

  attn_fwd<<<dim3(768), blk, 0, stream>>>(qb, kbuf, vtb, ao);

  gemm_bt64<<<dim3(12 * 64), blk, 0, stream>>>(
      ao, wt_proj, b_proj, x, x2, 8192, 768, 768);

  ln_rows<<<8192, blk, 0, stream>>>(x2, ln2_g, ln2_b, hbuf);

  gemm_bt<2><<<dim3(24 * 64), blk, 0, stream>>>(
      hbuf, wt_fc, b_fc, nullptr, nullptr, ff, nullptr, nullptr, 8192, 3072, 768);

  gemm_bt64<<<dim3(12 * 64), blk, 0, stream>>>(
      ff, wt_fc2, b_fc2, x2, out, 8192, 768, 3072);
}

// Round 9
// 340.767 us; speedup vs baseline: 1.0797x; 1.0797x over previous
//
#include <hip/hip_runtime.h>
#include <hip/hip_bf16.h>
#include <stdint.h>

#define S_LEN 1024
#define E_DIM 768
#define H_N   12
#define FF_DIM 3072

typedef __hip_bfloat16 bf16;
using short8  = __attribute__((ext_vector_type(8))) short;
using short4v = __attribute__((ext_vector_type(4))) short;
using f32x4   = __attribute__((ext_vector_type(4))) float;

__device__ __forceinline__ void async_cp16(const void* g, void* l) {
  __builtin_amdgcn_global_load_lds(
      (__attribute__((address_space(1))) void*)(g),
      (__attribute__((address_space(3))) void*)(l), 16, 0, 0);
}

// -------- fused weight transpose + cast (all 4 weights, one launch) ----------
__global__ __launch_bounds__(256) void wcastT_all(
    const float* __restrict__ wa, const float* __restrict__ wp,
    const float* __restrict__ wf, const float* __restrict__ wf2,
    bf16* __restrict__ oa, bf16* __restrict__ op,
    bf16* __restrict__ of, bf16* __restrict__ of2) {
  __shared__ float t[32][33];
  int bid = blockIdx.x;
  const float* w; bf16* wt; int K, N, bx, by;
  if (bid < 1728)      { w = wa;  wt = oa;  K = 768;  N = 2304; int r = bid;        bx = r % 72; by = r / 72; }
  else if (bid < 2304) { w = wp;  wt = op;  K = 768;  N = 768;  int r = bid - 1728; bx = r % 24; by = r / 24; }
  else if (bid < 4608) { w = wf;  wt = of;  K = 768;  N = 3072; int r = bid - 2304; bx = r % 96; by = r / 96; }
  else                 { w = wf2; wt = of2; K = 3072; N = 768;  int r = bid - 4608; bx = r % 24; by = r / 24; }
  int x = threadIdx.x & 31;
  int y = threadIdx.x >> 5;     // 0..7
  for (int i = y; i < 32; i += 8)
    t[i][x] = w[(size_t)(by * 32 + i) * N + bx * 32 + x];
  __syncthreads();
  for (int i = y; i < 32; i += 8)
    wt[(size_t)(bx * 32 + i) * K + by * 32 + x] = __float2bfloat16(t[x][i]);
}

// ---------------- layernorm over E=768, out bf16 -----------------------------
__global__ __launch_bounds__(256) void ln_rows(const float* __restrict__ x,
                                               const float* __restrict__ g,
                                               const float* __restrict__ b,
                                               bf16* __restrict__ out) {
  int row = blockIdx.x;
  int tid = threadIdx.x;
  const float* xr = x + (size_t)row * E_DIM;
  float v0 = xr[tid], v1 = xr[tid + 256], v2 = xr[tid + 512];
  float s = v0 + v1 + v2;
  float ss = v0 * v0 + v1 * v1 + v2 * v2;
  for (int o = 32; o > 0; o >>= 1) {
    s  += __shfl_down(s, o);
    ss += __shfl_down(ss, o);
  }
  __shared__ float ps[4], pq[4];
  int wv = tid >> 6;
  if ((tid & 63) == 0) { ps[wv] = s; pq[wv] = ss; }
  __syncthreads();
  s  = ps[0] + ps[1] + ps[2] + ps[3];
  ss = pq[0] + pq[1] + pq[2] + pq[3];
  float mu  = s * (1.0f / E_DIM);
  float var = ss * (1.0f / E_DIM) - mu * mu;
  float rs  = rsqrtf(var + 1e-5f);
  bf16* orow = out + (size_t)row * E_DIM;
  orow[tid]       = __float2bfloat16((v0 - mu) * rs * g[tid]       + b[tid]);
  orow[tid + 256] = __float2bfloat16((v1 - mu) * rs * g[tid + 256] + b[tid + 256]);
  orow[tid + 512] = __float2bfloat16((v2 - mu) * rs * g[tid + 512] + b[tid + 512]);
}

// ---------------- GEMM 128x128: C[M,N] = A[M,K] @ Bt[N,K]^T ------------------
// Register-prefetch pipeline: single 32 KB LDS tile (high occupancy), next
// K-tile prefetched into VGPRs via global_load_dwordx4 issued right after the
// tile-ready barrier; ds_write at next iteration top (vmcnt wait lands after
// a full MFMA phase). XOR-swizzled LDS columns; XCD-aware 1-D grid.
// MFMA operands swapped: lane's 4 acc regs = 4 consecutive N-cols of one row.
// MODE 0: qkv scatter; MODE 2: gelu -> bf16.
template <int MODE>
__global__ __launch_bounds__(256) void gemm_bt(
    const bf16* __restrict__ A, const bf16* __restrict__ Bt,
    const float* __restrict__ bias, const float* __restrict__ resid,
    float* __restrict__ outf, bf16* __restrict__ ob0, bf16* __restrict__ ob1,
    bf16* __restrict__ ob2, int M, int N, int K) {
  __shared__ bf16 As[128 * 64];   // 16 KB
  __shared__ bf16 Bs[128 * 64];   // 16 KB
  int tid = threadIdx.x;
  int wave = tid >> 6, lane = tid & 63;
  int quad = lane >> 4, l16 = lane & 15;
  int gx = N >> 7;
  int flat = blockIdx.x;
  int y8 = flat & 7;
  int q2 = flat >> 3;
  int bx = q2 % gx;
  int by = (q2 / gx) * 8 + y8;
  int m0 = by * 128, n0 = bx * 128;
  int wm = (wave & 1) * 64, wn = (wave >> 1) * 64;
  f32x4 acc[4][4];
  for (int i = 0; i < 4; i++)
    for (int j = 0; j < 4; j++)
      for (int r = 0; r < 4; r++) acc[i][j][r] = 0.f;

  int xs = l16 & 7;                 // fragment-read XOR key
  int srow = tid >> 3;              // staging row 0..31 (+32t)
  int scg = (((tid & 7) ^ (srow & 7)) << 3);  // swizzled global col (elems)
  const bf16* aptr = A  + (size_t)(m0 + srow) * K + scg;
  const bf16* bptr = Bt + (size_t)(n0 + srow) * K + scg;
  int ldst = srow * 64 + (tid & 7) * 8;       // LDS dest (elems)

  short8 pa[4], pb[4];
#pragma unroll
  for (int t = 0; t < 4; t++) {
    pa[t] = *(const short8*)(aptr + (size_t)t * 32 * K);
    pb[t] = *(const short8*)(bptr + (size_t)t * 32 * K);
  }
  int nkb = K >> 6;
  for (int ik = 0; ik < nkb; ++ik) {
    __syncthreads();                // all waves done reading LDS (prev iter)
#pragma unroll
    for (int t = 0; t < 4; t++) {
      *(short8*)&As[ldst + t * 2048] = pa[t];
      *(short8*)&Bs[ldst + t * 2048] = pb[t];
    }
    __syncthreads();                // tile ready
    if (ik + 1 < nkb) {             // prefetch next tile into registers
      size_t ko = (size_t)(ik + 1) * 64;
#pragma unroll
      for (int t = 0; t < 4; t++) {
        pa[t] = *(const short8*)(aptr + ko + (size_t)t * 32 * K);
        pb[t] = *(const short8*)(bptr + ko + (size_t)t * 32 * K);
      }
    }
#pragma unroll
    for (int ks = 0; ks < 2; ks++) {
      int ko2 = (((ks * 4 + quad) ^ xs) << 3);
      short8 af[4], bfr[4];
      for (int i = 0; i < 4; i++)
        af[i] = *(const short8*)&As[(wm + i * 16 + l16) * 64 + ko2];
      for (int j = 0; j < 4; j++)
        bfr[j] = *(const short8*)&Bs[(wn + j * 16 + l16) * 64 + ko2];
      for (int i = 0; i < 4; i++)
        for (int j = 0; j < 4; j++)
          acc[i][j] = __builtin_amdgcn_mfma_f32_16x16x32_bf16(
              bfr[j], af[i], acc[i][j], 0, 0, 0);
    }
  }

  for (int j = 0; j < 4; j++) {
    int colb = n0 + wn + j * 16 + quad * 4;          // 4 consecutive cols
    f32x4 b4 = *(const f32x4*)&bias[colb];
    for (int i = 0; i < 4; i++) {
      int row = m0 + wm + i * 16 + l16;
      f32x4 v = acc[i][j] + b4;
      if (MODE == 0) {
        int nn = row >> 10, s = row & 1023;
        if (colb < 768) {
          int h = colb >> 6, db = colb & 63;
          short4v pk;
          for (int r = 0; r < 4; r++)
            pk[r] = __builtin_bit_cast(short, __float2bfloat16(v[r] * 0.125f));
          *(short4v*)&ob0[(((size_t)nn * H_N + h) * S_LEN + s) * 64 + db] = pk;
        } else if (colb < 1536) {
          int c = colb - 768;
          size_t nh2 = (size_t)nn * H_N + (c >> 6);
          int d = c & 63;
          short4v pk;
          for (int r = 0; r < 4; r++)
            pk[r] = __builtin_bit_cast(short, __float2bfloat16(v[r]));
          *(short4v*)&ob1[((nh2 * 8 + (d >> 3)) * S_LEN + s) * 8 + (d & 7)] = pk;
        } else {
          int c = colb - 1536;
          size_t nh2 = (size_t)nn * H_N + (c >> 6);
          int d0 = c & 63;
          for (int r = 0; r < 4; r++)
            ob2[((nh2 * 128 + (s >> 3)) * 64 + d0 + r) * 8 + (s & 7)] =
                __float2bfloat16(v[r]);
        }
      } else if (MODE == 2) {
        short4v pk;
        for (int r = 0; r < 4; r++) {
          float x = v[r];
          // tanh-form GELU: x * sigmoid(1.5957691*(x + 0.044715 x^3))
          float t = x * (1.59576912161f + 0.0713548162726f * x * x);
          float g = x * __builtin_amdgcn_rcpf(1.0f + __expf(-t));
          pk[r] = __builtin_bit_cast(short, __float2bfloat16(g));
        }
        *(short4v*)&ob0[(size_t)row * N + colb] = pk;
      }
    }
  }
}

// ---------------- GEMM 128x64 reg-prefetch: outf = A@Bt^T + bias + resid -----
// For N=768 GEMMs (proj, FC2): 768 blocks = 3/CU grid; 24 KB LDS + low VGPR
// gives ~5 resident blocks/CU worth of waves.
__global__ __launch_bounds__(256) void gemm_bt64(
    const bf16* __restrict__ A, const bf16* __restrict__ Bt,
    const float* __restrict__ bias, const float* __restrict__ resid,
    float* __restrict__ outf, int M, int N, int K) {
  __shared__ bf16 As[128 * 64];   // 16 KB
  __shared__ bf16 Bs[64 * 64];    //  8 KB
  int tid = threadIdx.x;
  int wave = tid >> 6, lane = tid & 63;
  int quad = lane >> 4, l16 = lane & 15;
  int gx = N >> 6;                  // 12
  int flat = blockIdx.x;
  int y8 = flat & 7;
  int q2 = flat >> 3;
  int bx = q2 % gx;
  int by = (q2 / gx) * 8 + y8;
  int m0 = by * 128, n0 = bx * 64;
  int wm = wave * 32;               // wave owns 32 M-rows, all 64 N-cols
  f32x4 acc[2][4];
  for (int i = 0; i < 2; i++)
    for (int j = 0; j < 4; j++)
      for (int r = 0; r < 4; r++) acc[i][j][r] = 0.f;

  int xs = l16 & 7;
  int srow = tid >> 3;
  int scg = (((tid & 7) ^ (srow & 7)) << 3);
  const bf16* aptr = A  + (size_t)(m0 + srow) * K + scg;
  const bf16* bptr = Bt + (size_t)(n0 + srow) * K + scg;
  int ldst = srow * 64 + (tid & 7) * 8;

  short8 pa[4], pb[2];
#pragma unroll
  for (int t = 0; t < 4; t++)
    pa[t] = *(const short8*)(aptr + (size_t)t * 32 * K);
#pragma unroll
  for (int t = 0; t < 2; t++)
    pb[t] = *(const short8*)(bptr + (size_t)t * 32 * K);

  int nkb = K >> 6;
  for (int ik = 0; ik < nkb; ++ik) {
    __syncthreads();
#pragma unroll
    for (int t = 0; t < 4; t++)
      *(short8*)&As[ldst + t * 2048] = pa[t];
#pragma unroll
    for (int t = 0; t < 2; t++)
      *(short8*)&Bs[ldst + t * 2048] = pb[t];
    __syncthreads();
    if (ik + 1 < nkb) {
      size_t ko = (size_t)(ik + 1) * 64;
#pragma unroll
      for (int t = 0; t < 4; t++)
        pa[t] = *(const short8*)(aptr + ko + (size_t)t * 32 * K);
#pragma unroll
      for (int t = 0; t < 2; t++)
        pb[t] = *(const short8*)(bptr + ko + (size_t)t * 32 * K);
    }
#pragma unroll
    for (int ks = 0; ks < 2; ks++) {
      int ko2 = (((ks * 4 + quad) ^ xs) << 3);
      short8 af[2], bfr[4];
      for (int i = 0; i < 2; i++)
        af[i] = *(const short8*)&As[(wm + i * 16 + l16) * 64 + ko2];
      for (int j = 0; j < 4; j++)
        bfr[j] = *(const short8*)&Bs[(j * 16 + l16) * 64 + ko2];
      for (int i = 0; i < 2; i++)
        for (int j = 0; j < 4; j++)
          acc[i][j] = __builtin_amdgcn_mfma_f32_16x16x32_bf16(
              bfr[j], af[i], acc[i][j], 0, 0, 0);
    }
  }

  for (int j = 0; j < 4; j++) {
    int colb = n0 + j * 16 + quad * 4;
    f32x4 b4 = *(const f32x4*)&bias[colb];
    for (int i = 0; i < 2; i++) {
      int row = m0 + wm + i * 16 + l16;
      size_t idx = (size_t)row * N + colb;
      f32x4 rv = *(const f32x4*)&resid[idx];
      *(f32x4*)&outf[idx] = acc[i][j] + b4 + rv;
    }
  }
}

// ---------------- flash attention v4: paired q-tiles, pipelined K/V ----------
// Paired q-tiles a & 15-a (uniform 17 k-tiles/block). No-max softmax
// (acc init -10, exact shift). Head-per-XCD swizzle. K/V staging double-
// buffered: one barrier per k-tile, prefetch after fragment reads.
__global__ __launch_bounds__(256) void attn_fwd(
    const bf16* __restrict__ q, const bf16* __restrict__ kg,
    const bf16* __restrict__ vg, bf16* __restrict__ out) {
  __shared__ bf16 kt2[2][8 * 64 * 8];  // 16 KB
  __shared__ bf16 vt2[2][8 * 64 * 8];  // 16 KB
  __shared__ bf16 pba[4][16 * 68];     // per-wave P, tile a (8.5 KB)
  __shared__ bf16 pbb[4][16 * 68];     // per-wave P, tile b (8.5 KB)
  int flat = blockIdx.x;             // 768 blocks
  int xcd = flat & 7;
  int j = flat >> 3;                 // 0..95
  int a = j & 7;                     // low q-tile 0..7
  int g = j >> 3;                    // 0..11
  int nh = xcd * 12 + g;             // head: all its blocks share flat&7
  int b = 15 - a;                    // high q-tile 8..15
  int n = nh / H_N, h = nh % H_N;
  int tid = threadIdx.x, wave = tid >> 6, lane = tid & 63;
  int quad = lane >> 4, l16 = lane & 15;
  const bf16* qp = q  + (size_t)nh * S_LEN * 64;
  const bf16* kp = kg + (size_t)nh * 8 * S_LEN * 8;
  const bf16* vp = vg + (size_t)nh * 128 * 64 * 8;
  int qra = a * 64 + wave * 16;      // tile-a wave rows; lane's q = qra + l16
  int qrb = b * 64 + wave * 16;

  short8 qfa[2], qfb[2];
  qfa[0] = *(const short8*)&qp[(size_t)(qra + l16) * 64 + quad * 8];
  qfa[1] = *(const short8*)&qp[(size_t)(qra + l16) * 64 + 32 + quad * 8];
  qfb[0] = *(const short8*)&qp[(size_t)(qrb + l16) * 64 + quad * 8];
  qfb[1] = *(const short8*)&qp[(size_t)(qrb + l16) * 64 + 32 + quad * 8];

  // staging pointers: slot s = t*256+tid, c = s>>6 = t*4 + (tid>>6), e = tid&63
  const bf16* kbase = kp + (((size_t)(tid >> 6) * S_LEN) + (tid & 63)) * 8;
  const bf16* vbase = vp + (((size_t)(tid >> 6) * 64) + (tid & 63)) * 8;

  f32x4 oaa[4], oab[4];              // O^T: d = dt*16+quad*4+r, q = l16
  for (int dt = 0; dt < 4; dt++)
    for (int r = 0; r < 4; r++) { oaa[dt][r] = 0.f; oab[dt][r] = 0.f; }
  float lia = 0.f, lib = 0.f;

  // prologue: stage k-tile 0 into buf 0
  {
    bf16* lk = &kt2[0][0] + tid * 8;
    bf16* lv = &vt2[0][0] + tid * 8;
#pragma unroll
    for (int t = 0; t < 2; ++t) {
      async_cp16(kbase + (size_t)t * 4 * S_LEN * 8, lk + t * 2048);
      async_cp16(vbase + (size_t)t * 2048, lv + t * 2048);
    }
  }

  for (int kb = 0; kb <= b; ++kb) {
    bool act_a = (kb <= a);
    int cur = kb & 1;
    __syncthreads();   // drains prefetch issued last iteration (cheap)

    // read ALL K/V fragments of current buffer into registers first
    short8 kf[2][4], vf[2][4];
#pragma unroll
    for (int ks = 0; ks < 2; ks++)
      for (int nt = 0; nt < 4; nt++) {
        kf[ks][nt] = *(const short8*)
            &kt2[cur][(size_t)((ks * 4 + quad) * 64 + nt * 16 + l16) * 8];
        vf[ks][nt] = *(const short8*)
            &vt2[cur][(size_t)((ks * 4 + quad) * 64 + nt * 16 + l16) * 8];
      }
    // prefetch next k-tile into the other buffer
    if (kb < b) {
      bf16* lk = &kt2[cur ^ 1][0] + tid * 8;
      bf16* lv = &vt2[cur ^ 1][0] + tid * 8;
      size_t kko = (size_t)(kb + 1) * 512;    // kb*64*8 elements
      size_t vko = (size_t)(kb + 1) * 4096;   // kb*8*64*8 elements
#pragma unroll
      for (int t = 0; t < 2; ++t) {
        async_cp16(kbase + kko + (size_t)t * 4 * S_LEN * 8, lk + t * 2048);
        async_cp16(vbase + vko + (size_t)t * 2048, lv + t * 2048);
      }
    }

    // S^T = K·Q^T for both tiles; acc starts at -10 (softmax shift)
    f32x4 sb4[4], sa4[4];
    for (int nt = 0; nt < 4; nt++) {
      for (int r = 0; r < 4; r++) { sb4[nt][r] = -10.f; sa4[nt][r] = -10.f; }
      for (int ks = 0; ks < 2; ks++) {
        sb4[nt] = __builtin_amdgcn_mfma_f32_16x16x32_bf16(kf[ks][nt], qfb[ks],
                                                          sb4[nt], 0, 0, 0);
        if (act_a)
          sa4[nt] = __builtin_amdgcn_mfma_f32_16x16x32_bf16(kf[ks][nt], qfa[ks],
                                                            sa4[nt], 0, 0, 0);
      }
    }
    if (kb == b) {   // diagonal of tile b
      int ql = wave * 16 + l16;
      for (int nt = 0; nt < 4; nt++)
        for (int r = 0; r < 4; r++)
          if (nt * 16 + quad * 4 + r > ql) sb4[nt][r] = -INFINITY;
    }
    if (kb == a) {   // diagonal of tile a
      int ql = wave * 16 + l16;
      for (int nt = 0; nt < 4; nt++)
        for (int r = 0; r < 4; r++)
          if (nt * 16 + quad * 4 + r > ql) sa4[nt][r] = -INFINITY;
    }

    // no-max softmax: p = e^{s-10}; row sum via 2 shuffles
    float rsb = 0.f;
    for (int nt = 0; nt < 4; nt++)
      for (int r = 0; r < 4; r++) {
        float p = __expf(sb4[nt][r]);
        sb4[nt][r] = p;
        rsb += p;
      }
    rsb += __shfl_xor(rsb, 16);
    rsb += __shfl_xor(rsb, 32);
    lib += rsb;
    bf16* pwb = pbb[wave];
    for (int nt = 0; nt < 4; nt++) {
      short4v pk;
      for (int r = 0; r < 4; r++)
        pk[r] = __builtin_bit_cast(short, __float2bfloat16(sb4[nt][r]));
      *(short4v*)&pwb[l16 * 68 + nt * 16 + quad * 4] = pk;
    }
    if (act_a) {
      float rsa = 0.f;
      for (int nt = 0; nt < 4; nt++)
        for (int r = 0; r < 4; r++) {
          float p = __expf(sa4[nt][r]);
          sa4[nt][r] = p;
          rsa += p;
        }
      rsa += __shfl_xor(rsa, 16);
      rsa += __shfl_xor(rsa, 32);
      lia += rsa;
      bf16* pwa = pba[wave];
      for (int nt = 0; nt < 4; nt++) {
        short4v pk;
        for (int r = 0; r < 4; r++)
          pk[r] = __builtin_bit_cast(short, __float2bfloat16(sa4[nt][r]));
        *(short4v*)&pwa[l16 * 68 + nt * 16 + quad * 4] = pk;
      }
    }
    asm volatile("s_waitcnt lgkmcnt(0)" ::: "memory");  // same-wave LDS RAW

    // O^T += V^T·P^T
    for (int ks = 0; ks < 2; ks++) {
      short8 pfb = *(const short8*)&pbb[wave][l16 * 68 + ks * 32 + quad * 8];
      short8 pfa;
      if (act_a) pfa = *(const short8*)&pba[wave][l16 * 68 + ks * 32 + quad * 8];
      for (int dt = 0; dt < 4; dt++) {
        oab[dt] = __builtin_amdgcn_mfma_f32_16x16x32_bf16(vf[ks][dt], pfb,
                                                          oab[dt], 0, 0, 0);
        if (act_a)
          oaa[dt] = __builtin_amdgcn_mfma_f32_16x16x32_bf16(vf[ks][dt], pfa,
                                                            oaa[dt], 0, 0, 0);
      }
    }
  }

  float inva = 1.0f / lia, invb = 1.0f / lib;
  int ta = n * S_LEN + qra + l16;
  int tb = n * S_LEN + qrb + l16;
  for (int dt = 0; dt < 4; dt++) {
    short4v ova, ovb;
    for (int r = 0; r < 4; r++) {
      ova[r] = __builtin_bit_cast(short, __float2bfloat16(oaa[dt][r] * inva));
      ovb[r] = __builtin_bit_cast(short, __float2bfloat16(oab[dt][r] * invb));
    }
    *(short4v*)&out[(size_t)ta * E_DIM + h * 64 + dt * 16 + quad * 4] = ova;
    *(short4v*)&out[(size_t)tb * E_DIM + h * 64 + dt * 16 + quad * 4] = ovb;
  }
}

extern "C" void kernel_launch(void* const* d_in, const int* in_sizes, int n_in,
                              void* d_out, int out_size, void* d_ws, size_t ws_size,
                              hipStream_t stream) {
  (void)in_sizes; (void)n_in; (void)out_size; (void)ws_size;
  const float* x      = (const float*)d_in[0];
  const float* ln1_g  = (const float*)d_in[1];
  const float* ln1_b  = (const float*)d_in[2];
  const float* ln2_g  = (const float*)d_in[3];
  const float* ln2_b  = (const float*)d_in[4];
  const float* w_attn = (const float*)d_in[5];
  const float* b_attn = (const float*)d_in[6];
  const float* w_proj = (const float*)d_in[7];
  const float* b_proj = (const float*)d_in[8];
  const float* w_fc   = (const float*)d_in[9];
  const float* b_fc   = (const float*)d_in[10];
  const float* w_fc2  = (const float*)d_in[11];
  const float* b_fc2  = (const float*)d_in[12];
  float* out = (float*)d_out;

  char* ws = (char*)d_ws;
  bf16* wt_attn = (bf16*)(ws);                 //  3,538,944 B
  bf16* wt_proj = (bf16*)(ws + 3538944);       //  1,179,648 B
  bf16* wt_fc   = (bf16*)(ws + 4718592);       //  4,718,592 B
  bf16* wt_fc2  = (bf16*)(ws + 9437184);       //  4,718,592 B
  bf16* hbuf    = (bf16*)(ws + 14155776);      // 12,582,912 B
  float* x2     = (float*)(ws + 26738688);     // 25,165,824 B
  bf16* qb      = (bf16*)(ws + 51904512);      // 12,582,912 B
  bf16* kbuf    = (bf16*)(ws + 64487424);      // 12,582,912 B (chunked kg)
  bf16* vtb     = (bf16*)(ws + 77070336);      // 12,582,912 B (chunked vg)
  bf16* ao      = (bf16*)(ws + 89653248);      // 12,582,912 B  (ends 102,236,160)
  bf16* ff      = qb;  // reuse q/k/v/ao region (50,331,648 B needed)

  dim3 blk(256);
  wcastT_all<<<dim3(6912), blk, 0, stream>>>(w_attn, w_proj, w_fc, w_fc2,
                                             wt_attn, wt_proj, wt_fc, wt_fc2);

  ln_rows<<<8192, blk, 0, stream>>>(x, ln1_g, ln1_b, hbuf);

  gemm_bt<0><<<dim3(18 * 64), blk, 0, stream>>>(
      hbuf, wt_attn, b_attn, nullptr, nullptr, qb, kbuf, vtb, 8192, 2304, 768);

  attn_fwd<<<dim3(768), blk, 0, stream>>>(qb, kbuf, vtb, ao);

  gemm_bt64<<<dim3(12 * 64), blk, 0, stream>>>(
      ao, wt_proj, b_proj, x, x2, 8192, 768, 768);

  ln_rows<<<8192, blk, 0, stream>>>(x2, ln2_g, ln2_b, hbuf);

  gemm_bt<2><<<dim3(24 * 64), blk, 0, stream>>>(
      hbuf, wt_fc, b_fc, nullptr, nullptr, ff, nullptr, nullptr, 8192, 3072, 768);

  gemm_bt64<<<dim3(12 * 64), blk, 0, stream>>>(
      ff, wt_fc2, b_fc2, x2, out, 8192, 768, 3072);
}